// Round 18
// baseline (5560.713 us; speedup 1.0000x reference)
//
#include <hip/hip_runtime.h>
#include <cstdint>
#include <cstddef>

#define MM 4096
#define NSTEP 50
#define DD 100
#define HID 512
#define K0P 128
#define SIGC 0.4f
#define RC 0.05f
#define BMR 16
#define NWG (MM / BMR)   // 256 WGs x 512 threads (8 waves), one per CU
#define GSC 16.0f        // backward-gradient prescale (exact: bwd chain is linear)
#define SPAN 3           // time steps per launch (51 = 3*17)

typedef long fp8x8;      // 8 x e4m3 in one i64 (2 VGPRs)
typedef float f32x4 __attribute__((ext_vector_type(4)));
union Pack4 { __bf16 h[4]; uint2 u2; };   // cos stash (bf16 in registers)

typedef const __attribute__((address_space(1))) void* gvp;
typedef __attribute__((address_space(3))) void* lvp;
static __device__ __forceinline__ void load_lds16(const void* g, void* l) {
    __builtin_amdgcn_global_load_lds((gvp)g, (lvp)l, 16, 0, 0);
}

template <int N>
static __device__ __forceinline__ void wait_vmcnt() {
    if constexpr (N == 0)      asm volatile("s_waitcnt vmcnt(0)" ::: "memory");
    else if constexpr (N == 1) asm volatile("s_waitcnt vmcnt(1)" ::: "memory");
    else if constexpr (N == 2) asm volatile("s_waitcnt vmcnt(2)" ::: "memory");
    else if constexpr (N == 4) asm volatile("s_waitcnt vmcnt(4)" ::: "memory");
    __builtin_amdgcn_sched_barrier(0);
}

static __device__ __forceinline__ unsigned char to_fp8(float x) {
    return (unsigned char)(__builtin_amdgcn_cvt_pk_fp8_f32(x, 0.f, 0, false) & 0xff);
}
static __device__ __forceinline__ unsigned pack4_fp8(float a, float b, float c, float d) {
    int w = __builtin_amdgcn_cvt_pk_fp8_f32(a, b, 0, false);
    w = __builtin_amdgcn_cvt_pk_fp8_f32(c, d, w, true);
    return (unsigned)w;
}

// ---------- weight prep (fp8) ----------
__global__ void k_transpose(const float* __restrict__ in, unsigned char* __restrict__ out,
                            int Ksrc, int Kpad, int N) {
    int idx = blockIdx.x * 256 + threadIdx.x;
    if (idx >= N * Kpad) return;
    int n = idx / Kpad, k = idx - n * Kpad;
    out[idx] = (k < Ksrc) ? to_fp8(in[k * N + n]) : (unsigned char)0;
}

__global__ void k_cast(const float* __restrict__ in, unsigned char* __restrict__ out,
                       int Rsrc, int Rpad, int C) {
    int idx = blockIdx.x * 256 + threadIdx.x;
    if (idx >= Rpad * C) return;
    int r = idx / C;
    out[idx] = (r < Rsrc) ? to_fp8(in[idx]) : (unsigned char)0;
}

// ---------- init: X0 = tile(Xi), tXg row [t0, X0, 0-pad] (linear fp8) ----------
__global__ __launch_bounds__(256) void k_init(const float* __restrict__ t,
                                              const float* __restrict__ Xi,
                                              float* __restrict__ X0,
                                              unsigned char* __restrict__ tXg) {
    int m = blockIdx.x * 4 + (threadIdx.x >> 6);
    int lane = threadIdx.x & 63;
    for (int ii = 0; ii < 2; ii++) {
        int d = lane + ii * 64;
        if (d < DD) {
            float x = Xi[d];
            X0[m * DD + d] = x;
            tXg[(size_t)m * K0P + 1 + d] = to_fp8(x);
        } else if (d < K0P - 1) {
            tXg[(size_t)m * K0P + 1 + d] = 0;
        }
    }
    if (lane == 0) tXg[(size_t)m * K0P] = to_fp8(t[m * (NSTEP + 1)]);
}

// ---------- one layer pass: fp8, 8-wave wave-private DMA pipeline, NJB=1 ----------
// C[m][n] = sum_k A[m][k]*B[n][k]; A: LDS swizzled fp8 [16][ASTR]; wave w streams
// rows [w*NBLK/8, +NBLK/8) of each [NBLK][64k] chunk through 3 wave-private LDS
// slices; counted-vmcnt depth-2 pipeline, no barriers. Accumulate over ALL k.
// EPI 0: fwd: v+=bias; sin->Rout (fp8), cos->stash regs (bf16)
// EPI 1: fwd L3: v+=bias; cos*W4*GSC->Rout; u partials -> u_lds atomics
// EPI 2: bwd: v*stash -> Rout (carries GSC)
// EPI 3: bwd L0: v/GSC (f32) -> Rout as Z [16][132] f32
template <int K, int NBLK, int ASTR, int EPI>
__device__ __forceinline__ void phaseP(
    int tid, const unsigned char* __restrict__ Bw,
    const char* __restrict__ Rin, char* __restrict__ Rout, char* __restrict__ Bb,
    const float* __restrict__ bias, const float* __restrict__ W4,
    Pack4 (&stash)[4], float* __restrict__ u_lds) {

    constexpr int NQ  = K / 64;          // k-chunks
    constexpr int NJ  = NBLK / 128;      // col frags per wave (4 fwd/bwd, 1 Z)
    constexpr int CB  = NBLK * 64;       // full chunk bytes (32KB or 8KB)
    constexpr int SB  = CB / 8;          // per-wave slice bytes (4KB or 1KB)
    constexpr int I   = SB / 1024;       // per-wave stage instrs (4 or 1)

    const int wave = tid >> 6, lane = tid & 63;
    const int lr = lane & 15, lg = lane >> 4;
    const int am = lr;
    const int wrow0 = wave * (NBLK / 8);

    int bRow[I], bG[I];
    #pragma unroll
    for (int it = 0; it < I; it++) {
        int c16 = it * 64 + lane;
        bRow[it] = c16 >> 2;
        bG[it]   = (c16 & 3) ^ ((bRow[it] >> 1) & 3);
    }

    #define STG(q)                                                              \
        {   char* dst_ = Bb + ((q) % 3) * CB + wave * SB;                       \
            _Pragma("unroll")                                                   \
            for (int it = 0; it < I; it++)                                      \
                load_lds16(Bw + (size_t)(wrow0 + bRow[it]) * K                  \
                               + (q) * 64 + bG[it] * 16,                        \
                           dst_ + it * 1024); }

    STG(0)
    if (NQ > 1) STG(1)

    float up = 0.f;
    f32x4 acc[NJ] = {};
    #pragma unroll
    for (int q = 0; q < NQ; q++) {
        if (q + 1 < NQ) wait_vmcnt<I>(); else wait_vmcnt<0>();
        if (q + 2 < NQ) STG(q + 2)
        const char* slot = Bb + (q % 3) * CB + wave * SB;
        #pragma unroll
        for (int ks = 0; ks < 2; ks++) {
            int kcA = q * 8 + ks * 4 + lg;
            fp8x8 aF = *(const fp8x8*)(Rin + am * ASTR +
                        ((((kcA >> 1) ^ (am & 7))) << 4) + (kcA & 1) * 8);
            int kcB = ks * 4 + lg;
            #pragma unroll
            for (int nj = 0; nj < NJ; nj++) {
                int rl = nj * 16 + lr;
                fp8x8 bF = *(const fp8x8*)(slot + rl * 64 +
                            ((((kcB >> 1) ^ ((rl >> 1) & 3))) << 4) + (kcB & 1) * 8);
                acc[nj] = __builtin_amdgcn_mfma_f32_16x16x32_fp8_fp8(
                    bF, aF, acc[nj], 0, 0, 0);
            }
        }
    }
    #undef STG

    // epilogue (acc holds full-K result)
    #pragma unroll
    for (int nj = 0; nj < NJ; nj++) {
        const int n0 = wrow0 + nj * 16 + lg * 4;
        if (EPI == 3) {
            f32x4 z = acc[nj];
            z *= (1.0f / GSC);
            *(f32x4*)((float*)Rout + am * 132 + n0) = z;
        } else {
            const int po = am * 512 + (((n0 >> 4) ^ (am & 7)) << 4) +
                           ((n0 >> 3) & 1) * 8 + (n0 & 7);
            if (EPI == 0) {
                f32x4 bv = *(const f32x4*)(bias + n0);
                float s[4], c[4];
                #pragma unroll
                for (int r = 0; r < 4; r++)
                    __sincosf(acc[nj][r] + bv[r], &s[r], &c[r]);
                *(unsigned*)(Rout + po) = pack4_fp8(s[0], s[1], s[2], s[3]);
                Pack4 pc;
                #pragma unroll
                for (int r = 0; r < 4; r++) pc.h[r] = (__bf16)c[r];
                stash[nj] = pc;
            } else if (EPI == 1) {
                f32x4 bv = *(const f32x4*)(bias + n0);
                f32x4 wv = *(const f32x4*)(W4 + n0);
                float g[4];
                #pragma unroll
                for (int r = 0; r < 4; r++) {
                    float s, c;
                    __sincosf(acc[nj][r] + bv[r], &s, &c);
                    up += s * wv[r];
                    g[r] = c * wv[r] * GSC;
                }
                *(unsigned*)(Rout + po) = pack4_fp8(g[0], g[1], g[2], g[3]);
            } else {  // EPI == 2
                Pack4 pm = stash[nj];
                *(unsigned*)(Rout + po) = pack4_fp8(
                    acc[nj][0] * (float)pm.h[0], acc[nj][1] * (float)pm.h[1],
                    acc[nj][2] * (float)pm.h[2], acc[nj][3] * (float)pm.h[3]);
            }
        }
    }

    if (EPI == 1) {
        up += __shfl_xor(up, 16);
        up += __shfl_xor(up, 32);
        if (lg == 0) atomicAdd(&u_lds[am], up);
    }
}

// ---------- per-span kernel: WG owns 16 rows, SPAN steps of fwd+bwd+Euler ----------
__global__ __launch_bounds__(512, 1) void mega(
    const float* __restrict__ t, const float* __restrict__ W,
    const unsigned char* __restrict__ wt0, const unsigned char* __restrict__ wt1,
    const unsigned char* __restrict__ wt2, const unsigned char* __restrict__ wt3,
    const unsigned char* __restrict__ wd0, const unsigned char* __restrict__ wd1,
    const unsigned char* __restrict__ wd2, const unsigned char* __restrict__ wd3,
    const float* __restrict__ b0, const float* __restrict__ b1,
    const float* __restrict__ b2, const float* __restrict__ b3,
    const float* __restrict__ W4, const float* __restrict__ b4,
    unsigned char* __restrict__ tXg, float* __restrict__ X,
    float* __restrict__ Ytil, float* __restrict__ accG, int n0) {

    extern __shared__ char lds[];
    char*  tXL   = lds;                      // 2KB  swizzled fp8 [16][128B]
    char*  R0    = lds + 2048;               // 8KB  act slot fp8 [16][512B]
    char*  R1    = lds + 10240;              // 8KB  act slot
    float* Zf    = (float*)(lds + 18432);    // [16][132] f32 = 8448B
    char*  Bb    = lds + 26880;              // 3 x 32KB chunk slots (wave-sliced)
    float* u_lds = (float*)(lds + 125184);   // 16 u + 8 red

    const int tid = threadIdx.x;
    const int wgrow = blockIdx.x * BMR;
    const int em = tid >> 5, edg = tid & 31, ed0 = edg * 4;
    const int grow = wgrow + em;
    const int lane = tid & 63, wave = tid >> 6;
    const float b4v = b4[0];

    Pack4 st0[4], st1[4], st2[4];

    // span-persistent state in registers
    float x[4];
    #pragma unroll
    for (int i = 0; i < 4; i++) {
        int d = ed0 + i;
        x[i] = (d < DD) ? X[grow * DD + d] : 0.f;
    }
    float ytil = Ytil[grow];     // valid when n0>=1; unused at n0==0
    float resid_l = 0.f;

    // stage tX global(linear) -> LDS(swizzled): tids 0-127
    if (tid < 128) {
        int m = tid >> 3, pc = tid & 7;
        load_lds16(tXg + (size_t)(wgrow + m) * K0P + ((pc ^ (m & 7)) << 4),
                   tXL + wave * 1024 + lane * 16);
    }
    __syncthreads();

    for (int s = 0; s < SPAN; s++) {
        const int n = n0 + s;

        // forward
        phaseP<128, 512, 128, 0>(tid, wt0, tXL, R0, Bb, b0, nullptr, st0, u_lds);
        __syncthreads();
        phaseP<512, 512, 512, 0>(tid, wt1, R0, R1, Bb, b1, nullptr, st1, u_lds);
        __syncthreads();
        phaseP<512, 512, 512, 0>(tid, wt2, R1, R0, Bb, b2, nullptr, st2, u_lds);
        __syncthreads();
        if (tid < BMR) u_lds[tid] = 0.f;
        __syncthreads();
        phaseP<512, 512, 512, 1>(tid, wt3, R0, R1, Bb, b3, W4, st0 /*unused*/, u_lds);
        __syncthreads();
        // backward (gradients carry GSC)
        phaseP<512, 512, 512, 2>(tid, wd3, R1, R0, Bb, nullptr, nullptr, st2, u_lds);
        __syncthreads();
        phaseP<512, 512, 512, 2>(tid, wd2, R0, R1, Bb, nullptr, nullptr, st1, u_lds);
        __syncthreads();
        phaseP<512, 512, 512, 2>(tid, wd1, R1, R0, Bb, nullptr, nullptr, st0, u_lds);
        __syncthreads();
        phaseP<512, 128, 512, 3>(tid, wd0, R0, (char*)Zf, Bb, nullptr, nullptr, st0, u_lds);
        __syncthreads();

        // Euler / terminal (row-local; x,ytil in registers); 32 threads/row
        float u_reg = u_lds[em] + b4v;
        if (n >= 1 && edg == 0) {
            float dd = u_reg - ytil;
            resid_l += dd * dd;
        }
        const float* Zs = Zf + em * 132;
        if (n < NSTEP) {
            float t0v = t[grow * (NSTEP + 1) + n];
            float t1v = t[grow * (NSTEP + 1) + n + 1];
            const float* Wr = W + ((size_t)grow * (NSTEP + 1) + n) * DD;
            float pXZ = 0.f, pZs = 0.f;
            #pragma unroll
            for (int i = 0; i < 4; i++) {
                int d = ed0 + i;
                if (d < DD) {
                    float z = Zs[1 + d];
                    float dWv = Wr[DD + d] - Wr[d];
                    float sdw = SIGC * x[i] * dWv;
                    pXZ += x[i] * z;
                    pZs += z * sdw;
                    x[i] += sdw;
                    unsigned char v8 = to_fp8(x[i]);
                    int c = 1 + d;
                    tXL[em * 128 + (((c >> 4) ^ (em & 7)) << 4) + (c & 15)] = v8;
                    tXg[(size_t)grow * K0P + c] = v8;
                }
            }
            pXZ += __shfl_xor(pXZ, 1); pXZ += __shfl_xor(pXZ, 2);
            pXZ += __shfl_xor(pXZ, 4); pXZ += __shfl_xor(pXZ, 8);
            pXZ += __shfl_xor(pXZ, 16);
            pZs += __shfl_xor(pZs, 1); pZs += __shfl_xor(pZs, 2);
            pZs += __shfl_xor(pZs, 4); pZs += __shfl_xor(pZs, 8);
            pZs += __shfl_xor(pZs, 16);
            if (edg == 0) {
                float phi = RC * (u_reg - pXZ);
                ytil = u_reg + phi * (t1v - t0v) + pZs;
                unsigned char t8 = to_fp8(t1v);
                tXL[em * 128 + ((em & 7) << 4)] = t8;   // col 0, swizzled
                tXg[(size_t)grow * K0P] = t8;
            }
        } else {
            float gX = 0.f, sD = 0.f;
            #pragma unroll
            for (int i = 0; i < 4; i++) {
                int d = ed0 + i;
                if (d < DD) {
                    float z = Zs[1 + d];
                    gX += x[i] * x[i];
                    float e = z - 2.f * x[i];
                    sD += e * e;
                }
            }
            gX += __shfl_xor(gX, 1); gX += __shfl_xor(gX, 2);
            gX += __shfl_xor(gX, 4); gX += __shfl_xor(gX, 8);
            gX += __shfl_xor(gX, 16);
            sD += __shfl_xor(sD, 1); sD += __shfl_xor(sD, 2);
            sD += __shfl_xor(sD, 4); sD += __shfl_xor(sD, 8);
            sD += __shfl_xor(sD, 16);
            if (edg == 0) {
                float e = u_reg - gX;
                resid_l += e * e + sD;
            }
        }
        __syncthreads();
    }

    // span end: write back state for next launch
    #pragma unroll
    for (int i = 0; i < 4; i++) {
        int d = ed0 + i;
        if (d < DD) X[grow * DD + d] = x[i];
    }
    if (edg == 0) Ytil[grow] = ytil;

    // reduce resid across the WG -> one atomic per launch
    float r = resid_l;
    r += __shfl_xor(r, 32);
    r += __shfl_xor(r, 16);
    r += __shfl_xor(r, 8);
    r += __shfl_xor(r, 4);
    r += __shfl_xor(r, 2);
    r += __shfl_xor(r, 1);
    float* red = u_lds + 16;
    if (lane == 0) red[wave] = r;
    __syncthreads();
    if (tid == 0) {
        float s = 0.f;
        #pragma unroll
        for (int i = 0; i < 8; i++) s += red[i];
        atomicAdd(accG, s);
    }
}

__global__ void k_final(const float* __restrict__ acc, float* __restrict__ out) {
    out[0] = acc[0] / (float)MM;
}

// ---------- host ----------
extern "C" void kernel_launch(void* const* d_in, const int* in_sizes, int n_in,
                              void* d_out, int out_size, void* d_ws, size_t ws_size,
                              hipStream_t stream) {
    (void)in_sizes; (void)n_in; (void)out_size; (void)ws_size;
    const float* t  = (const float*)d_in[0];
    const float* W  = (const float*)d_in[1];
    const float* Xi = (const float*)d_in[2];
    const float* Wm[5];
    const float* bb[5];
    for (int i = 0; i < 5; i++) {
        Wm[i] = (const float*)d_in[3 + 2 * i];
        bb[i] = (const float*)d_in[4 + 2 * i];
    }

    char* p = (char*)d_ws;
    auto alloc = [&](size_t bytes) -> void* {
        void* r = (void*)p;
        p += (bytes + 255) & ~(size_t)255;
        return r;
    };

    unsigned char* wt[4];
    wt[0] = (unsigned char*)alloc((size_t)HID * K0P);
    for (int i = 1; i < 4; i++) wt[i] = (unsigned char*)alloc((size_t)HID * HID);
    unsigned char* wd[4];
    wd[0] = (unsigned char*)alloc((size_t)K0P * HID);
    for (int i = 1; i < 4; i++) wd[i] = (unsigned char*)alloc((size_t)HID * HID);
    unsigned char* tXg = (unsigned char*)alloc((size_t)MM * K0P);
    float* X    = (float*)alloc((size_t)MM * DD * 4);
    float* Ytil = (float*)alloc((size_t)MM * 4);
    float* acc  = (float*)alloc(256);

    hipMemsetAsync(acc, 0, 256, stream);

    // weight prep: wt = W^T (N x Kpad) fwd; wd = W (Npad x K) bwd — fp8
    k_transpose<<<(HID * K0P + 255) / 256, 256, 0, stream>>>(Wm[0], wt[0], 101, K0P, HID);
    for (int i = 1; i < 4; i++)
        k_transpose<<<(HID * HID + 255) / 256, 256, 0, stream>>>(Wm[i], wt[i], HID, HID, HID);
    k_cast<<<(K0P * HID + 255) / 256, 256, 0, stream>>>(Wm[0], wd[0], 101, K0P, HID);
    for (int i = 1; i < 4; i++)
        k_cast<<<(HID * HID + 255) / 256, 256, 0, stream>>>(Wm[i], wd[i], HID, HID, HID);

    k_init<<<MM / 4, 256, 0, stream>>>(t, Xi, X, tXg);

    const int LDSB = 125440;
    hipFuncSetAttribute((const void*)mega,
                        hipFuncAttributeMaxDynamicSharedMemorySize, LDSB);

    for (int n0 = 0; n0 <= NSTEP; n0 += SPAN) {
        mega<<<dim3(NWG), dim3(512), LDSB, stream>>>(
            t, W,
            wt[0], wt[1], wt[2], wt[3],
            wd[0], wd[1], wd[2], wd[3],
            bb[0], bb[1], bb[2], bb[3],
            Wm[4], bb[4],
            tXg, X, Ytil, acc, n0);
    }

    k_final<<<1, 1, 0, stream>>>(acc, (float*)d_out);
}

// Round 19
// 1497.418 us; speedup vs baseline: 3.7135x; 3.7135x over previous
//
#include <hip/hip_runtime.h>
#include <cstdint>
#include <cstddef>

#define MM 4096
#define NSTEP 50
#define DD 100
#define HID 512
#define K0P 128
#define SIGC 0.4f
#define RC 0.05f
#define BMR 16
#define NWG (MM / BMR)   // 256 WGs x 512 threads (8 waves), one per CU
#define GSC 16.0f        // backward-gradient prescale (exact: bwd chain is linear)

typedef long fp8x8;      // 8 x e4m3 in one i64 (2 VGPRs)
typedef float f32x4 __attribute__((ext_vector_type(4)));
union Pack4 { __bf16 h[4]; uint2 u2; };   // cos stash (bf16 in registers)

typedef const __attribute__((address_space(1))) void* gvp;
typedef __attribute__((address_space(3))) void* lvp;
static __device__ __forceinline__ void load_lds16(const void* g, void* l) {
    __builtin_amdgcn_global_load_lds((gvp)g, (lvp)l, 16, 0, 0);
}

template <int N>
static __device__ __forceinline__ void wait_vmcnt() {
    if constexpr (N == 0)      asm volatile("s_waitcnt vmcnt(0)" ::: "memory");
    else if constexpr (N == 1) asm volatile("s_waitcnt vmcnt(1)" ::: "memory");
    else if constexpr (N == 2) asm volatile("s_waitcnt vmcnt(2)" ::: "memory");
    else if constexpr (N == 4) asm volatile("s_waitcnt vmcnt(4)" ::: "memory");
    __builtin_amdgcn_sched_barrier(0);
}

static __device__ __forceinline__ unsigned char to_fp8(float x) {
    return (unsigned char)(__builtin_amdgcn_cvt_pk_fp8_f32(x, 0.f, 0, false) & 0xff);
}
static __device__ __forceinline__ unsigned pack4_fp8(float a, float b, float c, float d) {
    int w = __builtin_amdgcn_cvt_pk_fp8_f32(a, b, 0, false);
    w = __builtin_amdgcn_cvt_pk_fp8_f32(c, d, w, true);
    return (unsigned)w;
}

// ---------- weight prep (fp8) ----------
__global__ void k_transpose(const float* __restrict__ in, unsigned char* __restrict__ out,
                            int Ksrc, int Kpad, int N) {
    int idx = blockIdx.x * 256 + threadIdx.x;
    if (idx >= N * Kpad) return;
    int n = idx / Kpad, k = idx - n * Kpad;
    out[idx] = (k < Ksrc) ? to_fp8(in[k * N + n]) : (unsigned char)0;
}

__global__ void k_cast(const float* __restrict__ in, unsigned char* __restrict__ out,
                       int Rsrc, int Rpad, int C) {
    int idx = blockIdx.x * 256 + threadIdx.x;
    if (idx >= Rpad * C) return;
    int r = idx / C;
    out[idx] = (r < Rsrc) ? to_fp8(in[idx]) : (unsigned char)0;
}

// ---------- init: X0 = tile(Xi), tXg row [t0, X0, 0-pad] (linear fp8) ----------
__global__ __launch_bounds__(256) void k_init(const float* __restrict__ t,
                                              const float* __restrict__ Xi,
                                              float* __restrict__ X0,
                                              unsigned char* __restrict__ tXg) {
    int m = blockIdx.x * 4 + (threadIdx.x >> 6);
    int lane = threadIdx.x & 63;
    for (int ii = 0; ii < 2; ii++) {
        int d = lane + ii * 64;
        if (d < DD) {
            float x = Xi[d];
            X0[m * DD + d] = x;
            tXg[(size_t)m * K0P + 1 + d] = to_fp8(x);
        } else if (d < K0P - 1) {
            tXg[(size_t)m * K0P + 1 + d] = 0;
        }
    }
    if (lane == 0) tXg[(size_t)m * K0P] = to_fp8(t[m * (NSTEP + 1)]);
}

// ---------- one layer pass: fp8, 8-wave wave-private DMA pipeline ----------
// Round-17-proven structure; changes: 4 LDS slots + prefetch depth 3, setprio.
// C[m][n] = sum_k A[m][k]*B[n][k]; A: LDS swizzled fp8 [16][ASTR]; wave w streams
// rows [w*NBLK/8, +NBLK/8) of each [NBLK][64k] fp8 chunk through 4 wave-private
// LDS slices; counted-vmcnt pipeline, no barriers.
// EPI 0: fwd: v+=bias; sin->Rout (fp8), cos->stash regs (bf16)
// EPI 1: fwd L3: v+=bias; cos*W4*GSC->Rout; u partials -> u_lds atomics
// EPI 2: bwd: v*stash -> Rout (carries GSC)
// EPI 3: bwd L0: v/GSC (f32) -> Rout as Z [16][132] f32
template <int K, int NBLK, int NJB, int ASTR, int EPI>
__device__ __forceinline__ void phaseP(
    int tid, const unsigned char* __restrict__ Bw,
    const char* __restrict__ Rin, char* __restrict__ Rout, char* __restrict__ Bb,
    const float* __restrict__ bias, const float* __restrict__ W4,
    Pack4 (&stash)[2][2], float* __restrict__ u_lds) {

    constexpr int NKB = K / 64;          // k-chunks per j-block
    constexpr int NJ  = NBLK / 128;      // col frags per wave (2 fwd/bwd, 1 Z)
    constexpr int CB  = NBLK * 64;       // full chunk bytes (16KB or 8KB)
    constexpr int SB  = CB / 8;          // per-wave slice bytes (2KB or 1KB)
    constexpr int I   = SB / 1024;       // per-wave stage instrs (2 or 1)
    constexpr int NQ  = NJB * NKB;

    const int wave = tid >> 6, lane = tid & 63;
    const int lr = lane & 15, lg = lane >> 4;
    const int am = lr;
    const int wrow0 = wave * (NBLK / 8);   // this wave's row base in each chunk

    // per-instr source mapping within the wave's slice (pre-swizzled source).
    // rows are 64B (4 x 16B chunks); stage chunk p holds global chunk p^((row>>1)&3)
    int bRow[I], bG[I];
    #pragma unroll
    for (int it = 0; it < I; it++) {
        int c16 = it * 64 + lane;          // 16B-chunk index within slice
        bRow[it] = c16 >> 2;               // row within slice
        bG[it]   = (c16 & 3) ^ ((bRow[it] >> 1) & 3);
    }

    #define STG(q)                                                              \
        {   char* dst_ = Bb + ((q) % 4) * CB + wave * SB;                       \
            _Pragma("unroll")                                                   \
            for (int it = 0; it < I; it++)                                      \
                load_lds16(Bw + (size_t)(((q) / NKB) * NBLK + wrow0 + bRow[it]) * K \
                               + ((q) % NKB) * 64 + bG[it] * 16,                \
                           dst_ + it * 1024); }

    STG(0)
    if (NQ > 1) STG(1)
    if (NQ > 2) STG(2)

    float up = 0.f;
    f32x4 acc[NJ];
    #pragma unroll
    for (int q = 0; q < NQ; q++) {
        const int jb = q / NKB, kb = q % NKB;
        if (kb == 0) {
            #pragma unroll
            for (int nj = 0; nj < NJ; nj++) acc[nj] = f32x4{0.f, 0.f, 0.f, 0.f};
        }
        if (q + 3 <= NQ)      wait_vmcnt<2 * I>();
        else if (q + 2 == NQ) wait_vmcnt<I>();
        else                  wait_vmcnt<0>();
        if (q + 3 < NQ) STG(q + 3)
        const char* slot = Bb + (q % 4) * CB + wave * SB;
        __builtin_amdgcn_s_setprio(1);
        #pragma unroll
        for (int ks = 0; ks < 2; ks++) {
            int kcA = kb * 8 + ks * 4 + lg;   // A: 8-elem chunk index in row
            fp8x8 aF = *(const fp8x8*)(Rin + am * ASTR +
                        ((((kcA >> 1) ^ (am & 7))) << 4) + (kcA & 1) * 8);
            int kcB = ks * 4 + lg;            // B: 8-elem chunk within 64B row
            #pragma unroll
            for (int nj = 0; nj < NJ; nj++) {
                int rl = nj * 16 + lr;        // row within slice
                fp8x8 bF = *(const fp8x8*)(slot + rl * 64 +
                            ((((kcB >> 1) ^ ((rl >> 1) & 3))) << 4) + (kcB & 1) * 8);
                acc[nj] = __builtin_amdgcn_mfma_f32_16x16x32_fp8_fp8(
                    bF, aF, acc[nj], 0, 0, 0);
            }
        }
        __builtin_amdgcn_s_setprio(0);
        if (kb == NKB - 1) {
            #pragma unroll
            for (int nj = 0; nj < NJ; nj++) {
                const int n0 = jb * NBLK + wrow0 + nj * 16 + lg * 4;
                if (EPI == 3) {
                    f32x4 z = acc[nj];
                    z *= (1.0f / GSC);
                    *(f32x4*)((float*)Rout + am * 132 + n0) = z;
                } else {
                    const int po = am * 512 + (((n0 >> 4) ^ (am & 7)) << 4) +
                                   ((n0 >> 3) & 1) * 8 + (n0 & 7);
                    if (EPI == 0) {
                        f32x4 bv = *(const f32x4*)(bias + n0);
                        float s[4], c[4];
                        #pragma unroll
                        for (int r = 0; r < 4; r++)
                            __sincosf(acc[nj][r] + bv[r], &s[r], &c[r]);
                        *(unsigned*)(Rout + po) = pack4_fp8(s[0], s[1], s[2], s[3]);
                        Pack4 pc;
                        #pragma unroll
                        for (int r = 0; r < 4; r++) pc.h[r] = (__bf16)c[r];
                        stash[jb][nj] = pc;
                    } else if (EPI == 1) {
                        f32x4 bv = *(const f32x4*)(bias + n0);
                        f32x4 wv = *(const f32x4*)(W4 + n0);
                        float g[4];
                        #pragma unroll
                        for (int r = 0; r < 4; r++) {
                            float s, c;
                            __sincosf(acc[nj][r] + bv[r], &s, &c);
                            up += s * wv[r];
                            g[r] = c * wv[r] * GSC;
                        }
                        *(unsigned*)(Rout + po) = pack4_fp8(g[0], g[1], g[2], g[3]);
                    } else {  // EPI == 2
                        Pack4 pm = stash[jb][nj];
                        *(unsigned*)(Rout + po) = pack4_fp8(
                            acc[nj][0] * (float)pm.h[0], acc[nj][1] * (float)pm.h[1],
                            acc[nj][2] * (float)pm.h[2], acc[nj][3] * (float)pm.h[3]);
                    }
                }
            }
        }
    }
    #undef STG

    if (EPI == 1) {
        up += __shfl_xor(up, 16);
        up += __shfl_xor(up, 32);
        if (lg == 0) atomicAdd(&u_lds[am], up);
    }
}

// ---------- per-step kernel: WG owns 16 rows, full fwd+bwd+Euler ----------
__global__ __launch_bounds__(512, 1) void mega(
    const float* __restrict__ t, const float* __restrict__ W,
    const unsigned char* __restrict__ wt0, const unsigned char* __restrict__ wt1,
    const unsigned char* __restrict__ wt2, const unsigned char* __restrict__ wt3,
    const unsigned char* __restrict__ wd0, const unsigned char* __restrict__ wd1,
    const unsigned char* __restrict__ wd2, const unsigned char* __restrict__ wd3,
    const float* __restrict__ b0, const float* __restrict__ b1,
    const float* __restrict__ b2, const float* __restrict__ b3,
    const float* __restrict__ W4, const float* __restrict__ b4,
    unsigned char* __restrict__ tXg, float* __restrict__ X,
    float* __restrict__ Ytil, float* __restrict__ accG, int n) {

    extern __shared__ char lds[];
    char*  tXL   = lds;                      // 2KB  swizzled fp8 [16][128B]
    char*  R0    = lds + 2048;               // 8KB  act slot fp8 [16][512B]
    char*  R1    = lds + 10240;              // 8KB  act slot
    float* Zf    = (float*)(lds + 18432);    // [16][132] f32 = 8448B
    char*  Bb    = lds + 27648;              // 4 x 16KB chunk slots (wave-sliced)
    float* u_lds = (float*)(lds + 93184);    // 16 u + 8 red

    const int tid = threadIdx.x;
    const int wgrow = blockIdx.x * BMR;
    const int em = tid >> 5, edg = tid & 31, ed0 = edg * 4;
    const int grow = wgrow + em;
    const int lane = tid & 63, wave = tid >> 6;
    const float b4v = b4[0];

    Pack4 st0[2][2], st1[2][2], st2[2][2];

    // stage tX global(linear) -> LDS(swizzled): tids 0-127, 1 instr/thread
    if (tid < 128) {
        int m = tid >> 3, pc = tid & 7;
        load_lds16(tXg + (size_t)(wgrow + m) * K0P + ((pc ^ (m & 7)) << 4),
                   tXL + wave * 1024 + lane * 16);
    }
    __syncthreads();

    // forward
    phaseP<128, 256, 2, 128, 0>(tid, wt0, tXL, R0, Bb, b0, nullptr, st0, u_lds);
    __syncthreads();
    phaseP<512, 256, 2, 512, 0>(tid, wt1, R0, R1, Bb, b1, nullptr, st1, u_lds);
    __syncthreads();
    phaseP<512, 256, 2, 512, 0>(tid, wt2, R1, R0, Bb, b2, nullptr, st2, u_lds);
    __syncthreads();
    if (tid < BMR) u_lds[tid] = 0.f;
    __syncthreads();
    phaseP<512, 256, 2, 512, 1>(tid, wt3, R0, R1, Bb, b3, W4, st0 /*unused*/, u_lds);
    __syncthreads();
    // backward (gradients carry GSC)
    phaseP<512, 256, 2, 512, 2>(tid, wd3, R1, R0, Bb, nullptr, nullptr, st2, u_lds);
    __syncthreads();
    phaseP<512, 256, 2, 512, 2>(tid, wd2, R0, R1, Bb, nullptr, nullptr, st1, u_lds);
    __syncthreads();
    phaseP<512, 256, 2, 512, 2>(tid, wd1, R1, R0, Bb, nullptr, nullptr, st0, u_lds);
    __syncthreads();
    phaseP<512, 128, 1, 512, 3>(tid, wd0, R0, (char*)Zf, Bb, nullptr, nullptr, st0, u_lds);
    __syncthreads();

    // Euler / terminal (row-local, fp32 state); 32 threads/row
    float u_reg = u_lds[em] + b4v;
    float resid_l = 0.f;
    if (n >= 1 && edg == 0) {
        float dd = u_reg - Ytil[grow];
        resid_l = dd * dd;
    }
    const float* Zs = Zf + em * 132;
    if (n < NSTEP) {
        float t0v = t[grow * (NSTEP + 1) + n];
        float t1v = t[grow * (NSTEP + 1) + n + 1];
        const float* Wr = W + ((size_t)grow * (NSTEP + 1) + n) * DD;
        float pXZ = 0.f, pZs = 0.f;
        #pragma unroll
        for (int i = 0; i < 4; i++) {
            int d = ed0 + i;
            if (d < DD) {
                float x0 = X[grow * DD + d];
                float z = Zs[1 + d];
                float dWv = Wr[DD + d] - Wr[d];
                float s = SIGC * x0 * dWv;
                pXZ += x0 * z;
                pZs += z * s;
                float x1 = x0 + s;
                X[grow * DD + d] = x1;
                tXg[(size_t)grow * K0P + 1 + d] = to_fp8(x1);
            }
        }
        pXZ += __shfl_xor(pXZ, 1); pXZ += __shfl_xor(pXZ, 2);
        pXZ += __shfl_xor(pXZ, 4); pXZ += __shfl_xor(pXZ, 8);
        pXZ += __shfl_xor(pXZ, 16);
        pZs += __shfl_xor(pZs, 1); pZs += __shfl_xor(pZs, 2);
        pZs += __shfl_xor(pZs, 4); pZs += __shfl_xor(pZs, 8);
        pZs += __shfl_xor(pZs, 16);
        if (edg == 0) {
            float phi = RC * (u_reg - pXZ);
            Ytil[grow] = u_reg + phi * (t1v - t0v) + pZs;
            tXg[(size_t)grow * K0P] = to_fp8(t1v);
        }
    } else {
        float gX = 0.f, sD = 0.f;
        #pragma unroll
        for (int i = 0; i < 4; i++) {
            int d = ed0 + i;
            if (d < DD) {
                float x0 = X[grow * DD + d];
                float z = Zs[1 + d];
                gX += x0 * x0;
                float e = z - 2.f * x0;
                sD += e * e;
            }
        }
        gX += __shfl_xor(gX, 1); gX += __shfl_xor(gX, 2);
        gX += __shfl_xor(gX, 4); gX += __shfl_xor(gX, 8);
        gX += __shfl_xor(gX, 16);
        sD += __shfl_xor(sD, 1); sD += __shfl_xor(sD, 2);
        sD += __shfl_xor(sD, 4); sD += __shfl_xor(sD, 8);
        sD += __shfl_xor(sD, 16);
        if (edg == 0) {
            float e = u_reg - gX;
            resid_l += e * e + sD;
        }
    }

    // reduce resid across the WG -> one atomic
    float r = resid_l;
    r += __shfl_xor(r, 32);
    r += __shfl_xor(r, 16);
    r += __shfl_xor(r, 8);
    r += __shfl_xor(r, 4);
    r += __shfl_xor(r, 2);
    r += __shfl_xor(r, 1);
    float* red = u_lds + 16;
    if (lane == 0) red[wave] = r;
    __syncthreads();
    if (tid == 0) {
        float s = 0.f;
        #pragma unroll
        for (int i = 0; i < 8; i++) s += red[i];
        atomicAdd(accG, s);
    }
}

__global__ void k_final(const float* __restrict__ acc, float* __restrict__ out) {
    out[0] = acc[0] / (float)MM;
}

// ---------- host ----------
extern "C" void kernel_launch(void* const* d_in, const int* in_sizes, int n_in,
                              void* d_out, int out_size, void* d_ws, size_t ws_size,
                              hipStream_t stream) {
    (void)in_sizes; (void)n_in; (void)out_size; (void)ws_size;
    const float* t  = (const float*)d_in[0];
    const float* W  = (const float*)d_in[1];
    const float* Xi = (const float*)d_in[2];
    const float* Wm[5];
    const float* bb[5];
    for (int i = 0; i < 5; i++) {
        Wm[i] = (const float*)d_in[3 + 2 * i];
        bb[i] = (const float*)d_in[4 + 2 * i];
    }

    char* p = (char*)d_ws;
    auto alloc = [&](size_t bytes) -> void* {
        void* r = (void*)p;
        p += (bytes + 255) & ~(size_t)255;
        return r;
    };

    unsigned char* wt[4];
    wt[0] = (unsigned char*)alloc((size_t)HID * K0P);
    for (int i = 1; i < 4; i++) wt[i] = (unsigned char*)alloc((size_t)HID * HID);
    unsigned char* wd[4];
    wd[0] = (unsigned char*)alloc((size_t)K0P * HID);
    for (int i = 1; i < 4; i++) wd[i] = (unsigned char*)alloc((size_t)HID * HID);
    unsigned char* tXg = (unsigned char*)alloc((size_t)MM * K0P);
    float* X    = (float*)alloc((size_t)MM * DD * 4);
    float* Ytil = (float*)alloc((size_t)MM * 4);
    float* acc  = (float*)alloc(256);

    hipMemsetAsync(acc, 0, 256, stream);

    // weight prep: wt = W^T (N x Kpad) fwd; wd = W (Npad x K) bwd — fp8
    k_transpose<<<(HID * K0P + 255) / 256, 256, 0, stream>>>(Wm[0], wt[0], 101, K0P, HID);
    for (int i = 1; i < 4; i++)
        k_transpose<<<(HID * HID + 255) / 256, 256, 0, stream>>>(Wm[i], wt[i], HID, HID, HID);
    k_cast<<<(K0P * HID + 255) / 256, 256, 0, stream>>>(Wm[0], wd[0], 101, K0P, HID);
    for (int i = 1; i < 4; i++)
        k_cast<<<(HID * HID + 255) / 256, 256, 0, stream>>>(Wm[i], wd[i], HID, HID, HID);

    k_init<<<MM / 4, 256, 0, stream>>>(t, Xi, X, tXg);

    const int LDSB = 93440;
    hipFuncSetAttribute((const void*)mega,
                        hipFuncAttributeMaxDynamicSharedMemorySize, LDSB);

    for (int n = 0; n <= NSTEP; n++) {
        mega<<<dim3(NWG), dim3(512), LDSB, stream>>>(
            t, W,
            wt[0], wt[1], wt[2], wt[3],
            wd[0], wd[1], wd[2], wd[3],
            bb[0], bb[1], bb[2], bb[3],
            Wm[4], bb[4],
            tXg, X, Ytil, acc, n);
    }

    k_final<<<1, 1, 0, stream>>>(acc, (float*)d_out);
}

// Round 20
// 1468.212 us; speedup vs baseline: 3.7874x; 1.0199x over previous
//
#include <hip/hip_runtime.h>
#include <cstdint>
#include <cstddef>

#define MM 4096
#define NSTEP 50
#define DD 100
#define HID 512
#define K0P 128
#define SIGC 0.4f
#define RC 0.05f
#define BMR 16
#define NWG (MM / BMR)   // 256 WGs x 512 threads (8 waves), one per CU
#define GSC 16.0f        // backward-gradient prescale (exact: bwd chain is linear)

typedef long fp8x8;      // 8 x e4m3 in one i64 (2 VGPRs)
typedef float f32x4 __attribute__((ext_vector_type(4)));
union Pack4 { __bf16 h[4]; uint2 u2; };   // cos stash stays bf16 in registers

typedef const __attribute__((address_space(1))) void* gvp;
typedef __attribute__((address_space(3))) void* lvp;
static __device__ __forceinline__ void load_lds16(const void* g, void* l) {
    __builtin_amdgcn_global_load_lds((gvp)g, (lvp)l, 16, 0, 0);
}

template <int N>
static __device__ __forceinline__ void wait_vmcnt() {
    if constexpr (N == 0)      asm volatile("s_waitcnt vmcnt(0)" ::: "memory");
    else if constexpr (N == 1) asm volatile("s_waitcnt vmcnt(1)" ::: "memory");
    else if constexpr (N == 2) asm volatile("s_waitcnt vmcnt(2)" ::: "memory");
    else if constexpr (N == 4) asm volatile("s_waitcnt vmcnt(4)" ::: "memory");
    __builtin_amdgcn_sched_barrier(0);
}

static __device__ __forceinline__ unsigned char to_fp8(float x) {
    return (unsigned char)(__builtin_amdgcn_cvt_pk_fp8_f32(x, 0.f, 0, false) & 0xff);
}
static __device__ __forceinline__ unsigned pack4_fp8(float a, float b, float c, float d) {
    int w = __builtin_amdgcn_cvt_pk_fp8_f32(a, b, 0, false);
    w = __builtin_amdgcn_cvt_pk_fp8_f32(c, d, w, true);
    return (unsigned)w;
}

// ---------- weight prep (round-6 indexing, fp8 output) ----------
__global__ void k_transpose(const float* __restrict__ in, unsigned char* __restrict__ out,
                            int Ksrc, int Kpad, int N) {
    int idx = blockIdx.x * 256 + threadIdx.x;
    if (idx >= N * Kpad) return;
    int n = idx / Kpad, k = idx - n * Kpad;
    out[idx] = (k < Ksrc) ? to_fp8(in[k * N + n]) : (unsigned char)0;
}

__global__ void k_cast(const float* __restrict__ in, unsigned char* __restrict__ out,
                       int Rsrc, int Rpad, int C) {
    int idx = blockIdx.x * 256 + threadIdx.x;
    if (idx >= Rpad * C) return;
    int r = idx / C;
    out[idx] = (r < Rsrc) ? to_fp8(in[idx]) : (unsigned char)0;
}

// ---------- init: X0 = tile(Xi), tXg row [t0, X0, 0-pad] (linear fp8) ----------
__global__ __launch_bounds__(256) void k_init(const float* __restrict__ t,
                                              const float* __restrict__ Xi,
                                              float* __restrict__ X0,
                                              unsigned char* __restrict__ tXg) {
    int m = blockIdx.x * 4 + (threadIdx.x >> 6);
    int lane = threadIdx.x & 63;
    for (int ii = 0; ii < 2; ii++) {
        int d = lane + ii * 64;
        if (d < DD) {
            float x = Xi[d];
            X0[m * DD + d] = x;
            tXg[(size_t)m * K0P + 1 + d] = to_fp8(x);
        } else if (d < K0P - 1) {
            tXg[(size_t)m * K0P + 1 + d] = 0;
        }
    }
    if (lane == 0) tXg[(size_t)m * K0P] = to_fp8(t[m * (NSTEP + 1)]);
}

// ---------- one layer pass: fp8, 8-wave wave-private DMA-pipelined B ----------
// C[m][n] = sum_k A[m][k]*B[n][k]; A: LDS swizzled fp8 [16][ASTR]; wave w streams
// rows [w*NBLK/8, +NBLK/8) of each [NBLK][64k] fp8 chunk through 3 wave-private
// LDS slices; counted-vmcnt depth-2 pipeline, no barriers (round-12/16 discipline).
// B-slice swizzle: 16B granule p ^= (row>>1)&3 (2-way bank, free).
// Act swizzle: 16B granule p ^= m&7 (2-way bank, free).
// EPI 0: fwd: v+=bias; sin->Rout (fp8), cos->stash regs (bf16)
// EPI 1: fwd L3: v+=bias; cos*W4*GSC->Rout; u partials -> u_lds atomics
// EPI 2: bwd: v*stash -> Rout (carries GSC)
// EPI 3: bwd L0: v/GSC (f32) -> Rout as Z [16][132] f32
template <int K, int NBLK, int NJB, int ASTR, int EPI>
__device__ __forceinline__ void phaseP(
    int tid, const unsigned char* __restrict__ Bw,
    const char* __restrict__ Rin, char* __restrict__ Rout, char* __restrict__ Bb,
    const float* __restrict__ bias, const float* __restrict__ W4,
    Pack4 (&stash)[2][2], float* __restrict__ u_lds) {

    constexpr int NKB = K / 64;          // k-chunks per j-block
    constexpr int NJ  = NBLK / 128;      // col frags per wave (2 fwd/bwd, 1 Z)
    constexpr int CB  = NBLK * 64;       // full chunk bytes (16KB or 8KB)
    constexpr int SB  = CB / 8;          // per-wave slice bytes (2KB or 1KB)
    constexpr int I   = SB / 1024;       // per-wave stage instrs (2 or 1)
    constexpr int NQ  = NJB * NKB;

    const int wave = tid >> 6, lane = tid & 63;
    const int lr = lane & 15, lg = lane >> 4;
    const int am = lr;
    const int wrow0 = wave * (NBLK / 8);   // this wave's row base in each chunk

    // per-instr source mapping within the wave's slice (pre-swizzled source).
    // rows are 64B (4 x 16B chunks); stage chunk p holds global chunk p^((row>>1)&3)
    int bRow[I], bG[I];
    #pragma unroll
    for (int it = 0; it < I; it++) {
        int c16 = it * 64 + lane;          // 16B-chunk index within slice
        bRow[it] = c16 >> 2;               // row within slice
        bG[it]   = (c16 & 3) ^ ((bRow[it] >> 1) & 3);
    }

    #define STG(q)                                                              \
        {   char* dst_ = Bb + ((q) % 3) * CB + wave * SB;                       \
            _Pragma("unroll")                                                   \
            for (int it = 0; it < I; it++)                                      \
                load_lds16(Bw + (size_t)(((q) / NKB) * NBLK + wrow0 + bRow[it]) * K \
                               + ((q) % NKB) * 64 + bG[it] * 16,                \
                           dst_ + it * 1024); }

    STG(0)
    if (NQ > 1) STG(1)

    float up = 0.f;
    f32x4 acc[NJ];
    #pragma unroll
    for (int q = 0; q < NQ; q++) {
        const int jb = q / NKB, kb = q % NKB;
        if (kb == 0) {
            #pragma unroll
            for (int nj = 0; nj < NJ; nj++) acc[nj] = f32x4{0.f, 0.f, 0.f, 0.f};
        }
        if (q + 1 < NQ) wait_vmcnt<I>(); else wait_vmcnt<0>();
        if (q + 2 < NQ) STG(q + 2)
        const char* slot = Bb + (q % 3) * CB + wave * SB;
        #pragma unroll
        for (int ks = 0; ks < 2; ks++) {
            int kcA = kb * 8 + ks * 4 + lg;   // A: 8-elem chunk index in row
            fp8x8 aF = *(const fp8x8*)(Rin + am * ASTR +
                        ((((kcA >> 1) ^ (am & 7))) << 4) + (kcA & 1) * 8);
            int kcB = ks * 4 + lg;            // B: 8-elem chunk within 64B row
            #pragma unroll
            for (int nj = 0; nj < NJ; nj++) {
                int rl = nj * 16 + lr;        // row within slice
                fp8x8 bF = *(const fp8x8*)(slot + rl * 64 +
                            ((((kcB >> 1) ^ ((rl >> 1) & 3))) << 4) + (kcB & 1) * 8);
                acc[nj] = __builtin_amdgcn_mfma_f32_16x16x32_fp8_fp8(
                    bF, aF, acc[nj], 0, 0, 0);
            }
        }
        if (kb == NKB - 1) {
            #pragma unroll
            for (int nj = 0; nj < NJ; nj++) {
                const int n0 = jb * NBLK + wrow0 + nj * 16 + lg * 4;
                if (EPI == 3) {
                    f32x4 z = acc[nj];
                    z *= (1.0f / GSC);
                    *(f32x4*)((float*)Rout + am * 132 + n0) = z;
                } else {
                    const int po = am * 512 + (((n0 >> 4) ^ (am & 7)) << 4) +
                                   ((n0 >> 3) & 1) * 8 + (n0 & 7);
                    if (EPI == 0) {
                        f32x4 bv = *(const f32x4*)(bias + n0);
                        float s[4], c[4];
                        #pragma unroll
                        for (int r = 0; r < 4; r++)
                            __sincosf(acc[nj][r] + bv[r], &s[r], &c[r]);
                        *(unsigned*)(Rout + po) = pack4_fp8(s[0], s[1], s[2], s[3]);
                        Pack4 pc;
                        #pragma unroll
                        for (int r = 0; r < 4; r++) pc.h[r] = (__bf16)c[r];
                        stash[jb][nj] = pc;
                    } else if (EPI == 1) {
                        f32x4 bv = *(const f32x4*)(bias + n0);
                        f32x4 wv = *(const f32x4*)(W4 + n0);
                        float g[4];
                        #pragma unroll
                        for (int r = 0; r < 4; r++) {
                            float s, c;
                            __sincosf(acc[nj][r] + bv[r], &s, &c);
                            up += s * wv[r];
                            g[r] = c * wv[r] * GSC;
                        }
                        *(unsigned*)(Rout + po) = pack4_fp8(g[0], g[1], g[2], g[3]);
                    } else {  // EPI == 2
                        Pack4 pm = stash[jb][nj];
                        *(unsigned*)(Rout + po) = pack4_fp8(
                            acc[nj][0] * (float)pm.h[0], acc[nj][1] * (float)pm.h[1],
                            acc[nj][2] * (float)pm.h[2], acc[nj][3] * (float)pm.h[3]);
                    }
                }
            }
        }
    }
    #undef STG

    if (EPI == 1) {
        up += __shfl_xor(up, 16);
        up += __shfl_xor(up, 32);
        if (lg == 0) atomicAdd(&u_lds[am], up);
    }
}

// ---------- per-step kernel: WG owns 16 rows, full fwd+bwd+Euler ----------
__global__ __launch_bounds__(512, 1) void mega(
    const float* __restrict__ t, const float* __restrict__ W,
    const unsigned char* __restrict__ wt0, const unsigned char* __restrict__ wt1,
    const unsigned char* __restrict__ wt2, const unsigned char* __restrict__ wt3,
    const unsigned char* __restrict__ wd0, const unsigned char* __restrict__ wd1,
    const unsigned char* __restrict__ wd2, const unsigned char* __restrict__ wd3,
    const float* __restrict__ b0, const float* __restrict__ b1,
    const float* __restrict__ b2, const float* __restrict__ b3,
    const float* __restrict__ W4, const float* __restrict__ b4,
    unsigned char* __restrict__ tXg, float* __restrict__ X,
    float* __restrict__ Ytil, float* __restrict__ accG, int n) {

    extern __shared__ char lds[];
    char*  tXL   = lds;                      // 2KB  swizzled fp8 [16][128B]
    char*  R0    = lds + 2048;               // 8KB  act slot fp8 [16][512B]
    char*  R1    = lds + 10240;              // 8KB  act slot
    float* Zf    = (float*)(lds + 18432);    // [16][132] f32 = 8448B
    char*  Bb    = lds + 27648;              // 3 x 16KB chunk slots (wave-sliced)
    float* u_lds = (float*)(lds + 76800);    // 16 u + 8 red

    const int tid = threadIdx.x;
    const int wgrow = blockIdx.x * BMR;
    const int em = tid >> 5, edg = tid & 31, ed0 = edg * 4;
    const int grow = wgrow + em;
    const int lane = tid & 63, wave = tid >> 6;
    const float b4v = b4[0];

    Pack4 st0[2][2], st1[2][2], st2[2][2];

    // stage tX global(linear) -> LDS(swizzled): tids 0-127, 1 instr/thread
    if (tid < 128) {
        int m = tid >> 3, pc = tid & 7;
        load_lds16(tXg + (size_t)(wgrow + m) * K0P + ((pc ^ (m & 7)) << 4),
                   tXL + wave * 1024 + lane * 16);
    }
    __syncthreads();

    // forward
    phaseP<128, 256, 2, 128, 0>(tid, wt0, tXL, R0, Bb, b0, nullptr, st0, u_lds);
    __syncthreads();
    phaseP<512, 256, 2, 512, 0>(tid, wt1, R0, R1, Bb, b1, nullptr, st1, u_lds);
    __syncthreads();
    phaseP<512, 256, 2, 512, 0>(tid, wt2, R1, R0, Bb, b2, nullptr, st2, u_lds);
    __syncthreads();
    if (tid < BMR) u_lds[tid] = 0.f;
    __syncthreads();
    phaseP<512, 256, 2, 512, 1>(tid, wt3, R0, R1, Bb, b3, W4, st0 /*unused*/, u_lds);
    __syncthreads();
    // backward (gradients carry GSC)
    phaseP<512, 256, 2, 512, 2>(tid, wd3, R1, R0, Bb, nullptr, nullptr, st2, u_lds);
    __syncthreads();
    phaseP<512, 256, 2, 512, 2>(tid, wd2, R0, R1, Bb, nullptr, nullptr, st1, u_lds);
    __syncthreads();
    phaseP<512, 256, 2, 512, 2>(tid, wd1, R1, R0, Bb, nullptr, nullptr, st0, u_lds);
    __syncthreads();
    phaseP<512, 128, 1, 512, 3>(tid, wd0, R0, (char*)Zf, Bb, nullptr, nullptr, st0, u_lds);
    __syncthreads();

    // Euler / terminal (row-local, fp32 state); 32 threads/row
    float u_reg = u_lds[em] + b4v;
    float resid_l = 0.f;
    if (n >= 1 && edg == 0) {
        float dd = u_reg - Ytil[grow];
        resid_l = dd * dd;
    }
    const float* Zs = Zf + em * 132;
    if (n < NSTEP) {
        float t0v = t[grow * (NSTEP + 1) + n];
        float t1v = t[grow * (NSTEP + 1) + n + 1];
        const float* Wr = W + ((size_t)grow * (NSTEP + 1) + n) * DD;
        float pXZ = 0.f, pZs = 0.f;
        #pragma unroll
        for (int i = 0; i < 4; i++) {
            int d = ed0 + i;
            if (d < DD) {
                float x0 = X[grow * DD + d];
                float z = Zs[1 + d];
                float dWv = Wr[DD + d] - Wr[d];
                float s = SIGC * x0 * dWv;
                pXZ += x0 * z;
                pZs += z * s;
                float x1 = x0 + s;
                X[grow * DD + d] = x1;
                tXg[(size_t)grow * K0P + 1 + d] = to_fp8(x1);
            }
        }
        pXZ += __shfl_xor(pXZ, 1); pXZ += __shfl_xor(pXZ, 2);
        pXZ += __shfl_xor(pXZ, 4); pXZ += __shfl_xor(pXZ, 8);
        pXZ += __shfl_xor(pXZ, 16);
        pZs += __shfl_xor(pZs, 1); pZs += __shfl_xor(pZs, 2);
        pZs += __shfl_xor(pZs, 4); pZs += __shfl_xor(pZs, 8);
        pZs += __shfl_xor(pZs, 16);
        if (edg == 0) {
            float phi = RC * (u_reg - pXZ);
            Ytil[grow] = u_reg + phi * (t1v - t0v) + pZs;
            tXg[(size_t)grow * K0P] = to_fp8(t1v);
        }
    } else {
        float gX = 0.f, sD = 0.f;
        #pragma unroll
        for (int i = 0; i < 4; i++) {
            int d = ed0 + i;
            if (d < DD) {
                float x0 = X[grow * DD + d];
                float z = Zs[1 + d];
                gX += x0 * x0;
                float e = z - 2.f * x0;
                sD += e * e;
            }
        }
        gX += __shfl_xor(gX, 1); gX += __shfl_xor(gX, 2);
        gX += __shfl_xor(gX, 4); gX += __shfl_xor(gX, 8);
        gX += __shfl_xor(gX, 16);
        sD += __shfl_xor(sD, 1); sD += __shfl_xor(sD, 2);
        sD += __shfl_xor(sD, 4); sD += __shfl_xor(sD, 8);
        sD += __shfl_xor(sD, 16);
        if (edg == 0) {
            float e = u_reg - gX;
            resid_l += e * e + sD;
        }
    }

    // reduce resid across the WG -> one atomic
    float r = resid_l;
    r += __shfl_xor(r, 32);
    r += __shfl_xor(r, 16);
    r += __shfl_xor(r, 8);
    r += __shfl_xor(r, 4);
    r += __shfl_xor(r, 2);
    r += __shfl_xor(r, 1);
    float* red = u_lds + 16;
    if (lane == 0) red[wave] = r;
    __syncthreads();
    if (tid == 0) {
        float s = 0.f;
        #pragma unroll
        for (int i = 0; i < 8; i++) s += red[i];
        atomicAdd(accG, s);
    }
}

__global__ void k_final(const float* __restrict__ acc, float* __restrict__ out) {
    out[0] = acc[0] / (float)MM;
}

// ---------- host ----------
extern "C" void kernel_launch(void* const* d_in, const int* in_sizes, int n_in,
                              void* d_out, int out_size, void* d_ws, size_t ws_size,
                              hipStream_t stream) {
    (void)in_sizes; (void)n_in; (void)out_size; (void)ws_size;
    const float* t  = (const float*)d_in[0];
    const float* W  = (const float*)d_in[1];
    const float* Xi = (const float*)d_in[2];
    const float* Wm[5];
    const float* bb[5];
    for (int i = 0; i < 5; i++) {
        Wm[i] = (const float*)d_in[3 + 2 * i];
        bb[i] = (const float*)d_in[4 + 2 * i];
    }

    char* p = (char*)d_ws;
    auto alloc = [&](size_t bytes) -> void* {
        void* r = (void*)p;
        p += (bytes + 255) & ~(size_t)255;
        return r;
    };

    unsigned char* wt[4];
    wt[0] = (unsigned char*)alloc((size_t)HID * K0P);
    for (int i = 1; i < 4; i++) wt[i] = (unsigned char*)alloc((size_t)HID * HID);
    unsigned char* wd[4];
    wd[0] = (unsigned char*)alloc((size_t)K0P * HID);
    for (int i = 1; i < 4; i++) wd[i] = (unsigned char*)alloc((size_t)HID * HID);
    unsigned char* tXg = (unsigned char*)alloc((size_t)MM * K0P);
    float* X    = (float*)alloc((size_t)MM * DD * 4);
    float* Ytil = (float*)alloc((size_t)MM * 4);
    float* acc  = (float*)alloc(256);

    hipMemsetAsync(acc, 0, 256, stream);

    // weight prep: wt = W^T (N x Kpad) fwd; wd = W (Npad x K) bwd — fp8
    k_transpose<<<(HID * K0P + 255) / 256, 256, 0, stream>>>(Wm[0], wt[0], 101, K0P, HID);
    for (int i = 1; i < 4; i++)
        k_transpose<<<(HID * HID + 255) / 256, 256, 0, stream>>>(Wm[i], wt[i], HID, HID, HID);
    k_cast<<<(K0P * HID + 255) / 256, 256, 0, stream>>>(Wm[0], wd[0], 101, K0P, HID);
    for (int i = 1; i < 4; i++)
        k_cast<<<(HID * HID + 255) / 256, 256, 0, stream>>>(Wm[i], wd[i], HID, HID, HID);

    k_init<<<MM / 4, 256, 0, stream>>>(t, Xi, X, tXg);

    const int LDSB = 77056;
    hipFuncSetAttribute((const void*)mega,
                        hipFuncAttributeMaxDynamicSharedMemorySize, LDSB);

    for (int n = 0; n <= NSTEP; n++) {
        mega<<<dim3(NWG), dim3(512), LDSB, stream>>>(
            t, W,
            wt[0], wt[1], wt[2], wt[3],
            wd[0], wd[1], wd[2], wd[3],
            bb[0], bb[1], bb[2], bb[3],
            Wm[4], bb[4],
            tXg, X, Ytil, acc, n);
    }

    k_final<<<1, 1, 0, stream>>>(acc, (float*)d_out);
}